// Round 12
// baseline (87.914 us; speedup 1.0000x reference)
//
#include <hip/hip_runtime.h>
#include <stdint.h>

// Depthwise 5x5 SAME conv + gate residual: out = x*(alpha*conv + bias) + x
// x: (B=32, H=112, W=112, C=96) f32 NHWC. kernel: (5,5,96) f32.
//
// R12: wave-private LDS ring prefetch via global_load_lds DMA.
// Diagnosis (R1-R11): latency-bound. VALUBusy 36% == 4.65 waves/SIMD x
// (70 issue-cyc / ~900-cyc HBM latency): depth-1 register prefetch only
// covers the FMA block; the compiler sinks/spills anything deeper
// (R4/R6/R7/R10). global_load_lds is the one prefetch the compiler can't
// sink (side-effecting DMA) or spill (no VGPR destination):
//  - Each wave owns a private 3-slot x 5-tap x 64-lane f32 LDS ring
//    (3.75 KB/wave, 15 KB/block). NO barriers anywhere (wave-private).
//  - Body i: s_waitcnt vmcnt(10) [row i's 5 loads retired, rows i+1,i+2
//    + stores stay in flight], ds_read 5 taps (2 lanes/bank = free),
//    25 FMAs, NT store, DMA-issue row i+3 into the just-freed slot.
//    Prefetch distance = 3 bodies ~ 1400 cyc > 900 -> latency hidden.
//  - vmcnt retires in issue order; vmcnt(10) over-waits slightly vs the
//    exact 12 (stores interleaved) -- always safe.
//  - W-edges: clamped toff + zeroed weight columns (per-lane). H-edges:
//    wave-uniform rok zeroing at consume; DMA rows always clamped-valid.
//  - Kept: R3 decomposition (NSPLIT=3, 38/38/36), NT stores (R11, +5.6%).

#define CH 96
#define WI 112
#define HI 112
#define BATCH 32
#define NSPLIT 3
#define CHUNK_ROWS 38               // chunks: 38, 38, 36 -> nit 42/42/40
#define ROW_STRIDE (WI * CH)        // 10752
#define IMG_STRIDE (HI * WI * CH)   // 1204224

#define SLOTS   3
#define SLOT_F  (5 * 64)            // 5 taps x 64 lanes = 320 floats
#define WAVE_F  (SLOTS * SLOT_F)    // 960 floats / wave
#define NWAVES  4                   // 256 threads

__device__ __forceinline__ void dma4(const float* g, float* l) {
    __builtin_amdgcn_global_load_lds(
        (const __attribute__((address_space(1))) uint32_t*)g,
        (__attribute__((address_space(3))) uint32_t*)l,
        4, 0, 0);
}

__global__ __launch_bounds__(256) void dwconv_gate_dma(
    const float* __restrict__ x,
    const float* __restrict__ kern,
    const float* __restrict__ alpha,
    const float* __restrict__ bias,
    float* __restrict__ out)
{
    __shared__ float smem[NWAVES * WAVE_F];   // 15360 B

    const int tid  = threadIdx.x;
    const int lane = tid & 63;
    const int wave = tid >> 6;
    float* swave = &smem[wave * WAVE_F];      // wave-uniform

    const int gid = blockIdx.x * blockDim.x + tid;
    // gid -> (b, chunk, w, c); c innermost for coalescing
    const int c     = gid % CH;
    const int r1    = gid / CH;
    const int w     = r1 % WI;
    const int r2    = r1 / WI;
    const int chunk = r2 % NSPLIT;
    const int b     = r2 / NSPLIT;

    const float alphav = alpha[0];
    const float biasv  = bias[0];

    // Clamped tap offsets; OOB dx columns killed by zeroed weights.
    int toff[5];
#pragma unroll
    for (int dx = 0; dx < 5; ++dx) {
        const int ww = w + dx - 2;
        const int wc = ww < 0 ? 0 : (ww >= WI ? WI - 1 : ww);
        toff[dx] = (wc - w) * CH;
    }
    float wt[25];
#pragma unroll
    for (int i = 0; i < 25; ++i) {
        const int dx = i % 5;
        const int ww = w + dx - 2;
        wt[i] = ((ww >= 0) && (ww < WI)) ? kern[i * CH + c] : 0.f;
    }

    const int h0   = chunk * CHUNK_ROWS;
    const int rows = (chunk == NSPLIT - 1) ? (HI - h0) : CHUNK_ROWS;
    const int nit  = rows + 4;               // 42 / 42 / 40

    const float* px = x   + (size_t)b * IMG_STRIDE + (size_t)w * CH + c;
    float*       po = out + (size_t)b * IMG_STRIDE + (size_t)w * CH + c;

    // Issue all 5 tap DMAs for input row RIN (clamped) into SLOT.
#define ISSUE(SLOT, RIN) do {                                              \
        const int _q  = (RIN);                                             \
        const int _qc = _q < 0 ? 0 : (_q >= HI ? HI - 1 : _q);             \
        const float* _g = px + (size_t)_qc * ROW_STRIDE;                   \
        float* _d = swave + (SLOT) * SLOT_F;                               \
        dma4(_g + toff[0], _d);                                            \
        dma4(_g + toff[1], _d + 64);                                       \
        dma4(_g + toff[2], _d + 128);                                      \
        dma4(_g + toff[3], _d + 192);                                      \
        dma4(_g + toff[4], _d + 256);                                      \
    } while (0)

    // Prologue: 3 rows (15 loads) in flight.
    ISSUE(0, h0 - 2);
    ISSUE(1, h0 - 1);
    ISSUE(2, h0);

    float acc[5] = {0.f, 0.f, 0.f, 0.f, 0.f};
    float xp1 = 0.f, xp2 = 0.f;   // center-tap history (delay 2)

    // Body _i (slot = _i % 3): wait row _i's loads, consume, reissue slot
    // for row _i+3.
#define BODY(I, SLOT) do {                                                 \
        const int _i = (I);                                                \
        asm volatile("s_waitcnt vmcnt(10)" ::: "memory");                  \
        const int _rin = h0 - 2 + _i;                                      \
        const bool _rok = (_rin >= 0) && (_rin < HI);  /* wave-uniform */  \
        float t0, t1, t2, t3, t4;                                          \
        if (_rok) {                                                        \
            const float* _s = swave + (SLOT) * SLOT_F + lane;              \
            t0 = _s[0];   t1 = _s[64];  t2 = _s[128];                      \
            t3 = _s[192]; t4 = _s[256];                                    \
        } else {                                                           \
            t0 = 0.f; t1 = 0.f; t2 = 0.f; t3 = 0.f; t4 = 0.f;              \
        }                                                                  \
        _Pragma("unroll")                                                  \
        for (int j = 0; j < 5; ++j) {                                      \
            const int wb = (4 - j) * 5;                                    \
            acc[j] = fmaf(t0, wt[wb + 0], acc[j]);                         \
            acc[j] = fmaf(t1, wt[wb + 1], acc[j]);                         \
            acc[j] = fmaf(t2, wt[wb + 2], acc[j]);                         \
            acc[j] = fmaf(t3, wt[wb + 3], acc[j]);                         \
            acc[j] = fmaf(t4, wt[wb + 4], acc[j]);                         \
        }                                                                  \
        if (_i >= 4) {                                                     \
            const float g = fmaf(acc[0], alphav, biasv);                   \
            __builtin_nontemporal_store(                                   \
                fmaf(g, xp2, xp2),                                         \
                po + (ptrdiff_t)(h0 - 4 + _i) * ROW_STRIDE);               \
        }                                                                  \
        xp2 = xp1; xp1 = t2;                                               \
        acc[0] = acc[1]; acc[1] = acc[2]; acc[2] = acc[3];                 \
        acc[3] = acc[4]; acc[4] = 0.f;                                     \
        ISSUE(SLOT, h0 + 1 + _i);                                          \
    } while (0)

    int i = 0;
    for (; i + 3 <= nit; i += 3) {
        BODY(i + 0, 0);
        BODY(i + 1, 1);
        BODY(i + 2, 2);
    }
    if (i < nit) BODY(i, 0);      // nit % 3 is 0 or 1, never 2
#undef BODY
#undef ISSUE
}

extern "C" void kernel_launch(void* const* d_in, const int* in_sizes, int n_in,
                              void* d_out, int out_size, void* d_ws, size_t ws_size,
                              hipStream_t stream) {
    const float* x     = (const float*)d_in[0];
    const float* kern  = (const float*)d_in[1];
    const float* alpha = (const float*)d_in[2];
    const float* bias  = (const float*)d_in[3];
    float* out = (float*)d_out;

    const int total = BATCH * NSPLIT * WI * CH;   // 1,032,192 = 4032 * 256
    dim3 block(256);
    dim3 grid(total / 256);                       // 4032 blocks, 16128 waves
    hipLaunchKernelGGL(dwconv_gate_dma, grid, block, 0, stream,
                       x, kern, alpha, bias, out);
}

// Round 13
// 74.228 us; speedup vs baseline: 1.1844x; 1.1844x over previous
//
#include <hip/hip_runtime.h>
#include <stdint.h>

// Depthwise 5x5 SAME conv + gate residual: out = x*(alpha*conv + bias) + x
// x: (B=32, H=112, W=112, C=96) f32 NHWC. kernel: (5,5,96) f32.
//
// R13 = R12 (DMA LDS ring, VALUBusy 36->52%) + two levers:
//  1. Depth: SLOTS 3->4, vmcnt(10)->vmcnt(15): 3 rows in flight per wave
//     (3.8 KB) instead of 2. LDS 20.5 KB/block -> 7 blocks/CU, not binding.
//  2. XCD-aware block swizzle: 4032 = 8*504 exactly; each XCD gets 12
//     contiguous (b,chunk) units (42 blocks each sharing rows+halo ->
//     halo re-reads become L2 hits instead of HBM re-fetch).
//  - Wave-private 4-slot x 5-tap x 64-lane LDS ring, NO barriers.
//  - Body i: s_waitcnt vmcnt(15) [row i's 5 loads retired; rows i+1..i+3
//    + stores in flight], ds_read 5 taps, 25 FMAs, NT store, DMA row i+4
//    into the freed slot. Clamped rows ALWAYS issue 5 DMAs so the vmcnt
//    count per body is exact; OOB rows zeroed at consume (wave-uniform).
//  - W-edges: clamped toff + zeroed weight columns. NT stores (R11).

#define CH 96
#define WI 112
#define HI 112
#define BATCH 32
#define NSPLIT 3
#define CHUNK_ROWS 38               // chunks: 38, 38, 36 -> nit 42/42/40
#define ROW_STRIDE (WI * CH)        // 10752
#define IMG_STRIDE (HI * WI * CH)   // 1204224
#define NBLK (BATCH * NSPLIT * WI * CH / 256)   // 4032
#define BPX  (NBLK / 8)                          // 504 blocks per XCD

#define SLOTS   4
#define SLOT_F  (5 * 64)            // 5 taps x 64 lanes = 320 floats
#define WAVE_F  (SLOTS * SLOT_F)    // 1280 floats / wave
#define NWAVES  4                   // 256 threads

__device__ __forceinline__ void dma4(const float* g, float* l) {
    __builtin_amdgcn_global_load_lds(
        (const __attribute__((address_space(1))) uint32_t*)g,
        (__attribute__((address_space(3))) uint32_t*)l,
        4, 0, 0);
}

__global__ __launch_bounds__(256) void dwconv_gate_dma(
    const float* __restrict__ x,
    const float* __restrict__ kern,
    const float* __restrict__ alpha,
    const float* __restrict__ bias,
    float* __restrict__ out)
{
    __shared__ float smem[NWAVES * WAVE_F];   // 20480 B

    const int tid  = threadIdx.x;
    const int lane = tid & 63;
    const int wave = tid >> 6;
    float* swave = &smem[wave * WAVE_F];      // wave-uniform

    // XCD-aware swizzle: hw-bid k mod 8 -> XCD k; give XCD k the logical
    // range [k*504, (k+1)*504) so blocks sharing rows co-reside on one L2.
    const int bid = (blockIdx.x & 7) * BPX + (blockIdx.x >> 3);

    const int gid = bid * 256 + tid;
    // gid -> (b, chunk, w, c); c innermost for coalescing
    const int c     = gid % CH;
    const int r1    = gid / CH;
    const int w     = r1 % WI;
    const int r2    = r1 / WI;
    const int chunk = r2 % NSPLIT;
    const int b     = r2 / NSPLIT;

    const float alphav = alpha[0];
    const float biasv  = bias[0];

    // Clamped tap offsets; OOB dx columns killed by zeroed weights.
    int toff[5];
#pragma unroll
    for (int dx = 0; dx < 5; ++dx) {
        const int ww = w + dx - 2;
        const int wc = ww < 0 ? 0 : (ww >= WI ? WI - 1 : ww);
        toff[dx] = (wc - w) * CH;
    }
    float wt[25];
#pragma unroll
    for (int i = 0; i < 25; ++i) {
        const int dx = i % 5;
        const int ww = w + dx - 2;
        wt[i] = ((ww >= 0) && (ww < WI)) ? kern[i * CH + c] : 0.f;
    }

    const int h0   = chunk * CHUNK_ROWS;
    const int rows = (chunk == NSPLIT - 1) ? (HI - h0) : CHUNK_ROWS;
    const int nit  = rows + 4;               // 42 / 42 / 40

    const float* px = x   + (size_t)b * IMG_STRIDE + (size_t)w * CH + c;
    float*       po = out + (size_t)b * IMG_STRIDE + (size_t)w * CH + c;

    // Issue all 5 tap DMAs for input row RIN (clamped) into SLOT.
#define ISSUE(SLOT, RIN) do {                                              \
        const int _q  = (RIN);                                             \
        const int _qc = _q < 0 ? 0 : (_q >= HI ? HI - 1 : _q);             \
        const float* _g = px + (size_t)_qc * ROW_STRIDE;                   \
        float* _d = swave + (SLOT) * SLOT_F;                               \
        dma4(_g + toff[0], _d);                                            \
        dma4(_g + toff[1], _d + 64);                                       \
        dma4(_g + toff[2], _d + 128);                                      \
        dma4(_g + toff[3], _d + 192);                                      \
        dma4(_g + toff[4], _d + 256);                                      \
    } while (0)

    // Prologue: 4 rows (20 loads) in flight.
    ISSUE(0, h0 - 2);
    ISSUE(1, h0 - 1);
    ISSUE(2, h0);
    ISSUE(3, h0 + 1);

    float acc[5] = {0.f, 0.f, 0.f, 0.f, 0.f};
    float xp1 = 0.f, xp2 = 0.f;   // center-tap history (delay 2)

    // Body _i (slot = _i % 4): wait row _i's loads (drain to 15: rows
    // _i+1.._i+3 stay in flight), consume, reissue slot for row _i+4.
#define BODY(I, SLOT) do {                                                 \
        const int _i = (I);                                                \
        asm volatile("s_waitcnt vmcnt(15)" ::: "memory");                  \
        const int _rin = h0 - 2 + _i;                                      \
        const bool _rok = (_rin >= 0) && (_rin < HI);  /* wave-uniform */  \
        float t0, t1, t2, t3, t4;                                          \
        if (_rok) {                                                        \
            const float* _s = swave + (SLOT) * SLOT_F + lane;              \
            t0 = _s[0];   t1 = _s[64];  t2 = _s[128];                      \
            t3 = _s[192]; t4 = _s[256];                                    \
        } else {                                                           \
            t0 = 0.f; t1 = 0.f; t2 = 0.f; t3 = 0.f; t4 = 0.f;              \
        }                                                                  \
        _Pragma("unroll")                                                  \
        for (int j = 0; j < 5; ++j) {                                      \
            const int wb = (4 - j) * 5;                                    \
            acc[j] = fmaf(t0, wt[wb + 0], acc[j]);                         \
            acc[j] = fmaf(t1, wt[wb + 1], acc[j]);                         \
            acc[j] = fmaf(t2, wt[wb + 2], acc[j]);                         \
            acc[j] = fmaf(t3, wt[wb + 3], acc[j]);                         \
            acc[j] = fmaf(t4, wt[wb + 4], acc[j]);                         \
        }                                                                  \
        if (_i >= 4) {                                                     \
            const float g = fmaf(acc[0], alphav, biasv);                   \
            __builtin_nontemporal_store(                                   \
                fmaf(g, xp2, xp2),                                         \
                po + (ptrdiff_t)(h0 - 4 + _i) * ROW_STRIDE);               \
        }                                                                  \
        xp2 = xp1; xp1 = t2;                                               \
        acc[0] = acc[1]; acc[1] = acc[2]; acc[2] = acc[3];                 \
        acc[3] = acc[4]; acc[4] = 0.f;                                     \
        ISSUE(SLOT, h0 + 2 + _i);                                          \
    } while (0)

    int i = 0;
    for (; i + 4 <= nit; i += 4) {
        BODY(i + 0, 0);
        BODY(i + 1, 1);
        BODY(i + 2, 2);
        BODY(i + 3, 3);
    }
    // nit % 4 is 0 or 2, never 1/3.
    if (i < nit) {
        BODY(i + 0, 0);
        BODY(i + 1, 1);
    }
#undef BODY
#undef ISSUE
}

extern "C" void kernel_launch(void* const* d_in, const int* in_sizes, int n_in,
                              void* d_out, int out_size, void* d_ws, size_t ws_size,
                              hipStream_t stream) {
    const float* x     = (const float*)d_in[0];
    const float* kern  = (const float*)d_in[1];
    const float* alpha = (const float*)d_in[2];
    const float* bias  = (const float*)d_in[3];
    float* out = (float*)d_out;

    dim3 block(256);
    dim3 grid(NBLK);                              // 4032 blocks, 16128 waves
    hipLaunchKernelGGL(dwconv_gate_dma, grid, block, 0, stream,
                       x, kern, alpha, bias, out);
}

// Round 14
// 73.883 us; speedup vs baseline: 1.1899x; 1.0047x over previous
//
#include <hip/hip_runtime.h>
#include <stdint.h>

// Depthwise 5x5 SAME conv + gate residual: out = x*(alpha*conv + bias) + x
// x: (B=32, H=112, W=112, C=96) f32 NHWC. kernel: (5,5,96) f32.
//
// R14 = R13 (DMA LDS ring + XCD swizzle, 74.2us) + ONE change:
//  - Pipeline depth: SLOTS 4->6, vmcnt(15)->vmcnt(25). 5 rows in flight
//    per wave (6.4 KB) instead of 3. vmcnt = (SLOTS-1)*5 is safe even if
//    all interleaved NT stores retire before older loads (counter-based,
//    not FIFO-selective). LDS 30720 B/block -> 5 blocks/CU, above the
//    ~3.2 measured residency -> not newly binding.
//  - Everything else byte-identical to R13: wave-private LDS ring, no
//    barriers; XCD-aware swizzle (4032 = 8*504, contiguous (b,chunk)
//    ranges per XCD -> FETCH 77MB); clamped toff + zeroed weight columns;
//    wave-uniform H-edge zeroing at consume; NT stores; NSPLIT=3.

#define CH 96
#define WI 112
#define HI 112
#define BATCH 32
#define NSPLIT 3
#define CHUNK_ROWS 38               // chunks: 38, 38, 36 -> nit 42/42/40
#define ROW_STRIDE (WI * CH)        // 10752
#define IMG_STRIDE (HI * WI * CH)   // 1204224
#define NBLK (BATCH * NSPLIT * WI * CH / 256)   // 4032
#define BPX  (NBLK / 8)                          // 504 blocks per XCD

#define SLOTS   6
#define SLOT_F  (5 * 64)            // 5 taps x 64 lanes = 320 floats
#define WAVE_F  (SLOTS * SLOT_F)    // 1920 floats / wave
#define NWAVES  4                   // 256 threads

__device__ __forceinline__ void dma4(const float* g, float* l) {
    __builtin_amdgcn_global_load_lds(
        (const __attribute__((address_space(1))) uint32_t*)g,
        (__attribute__((address_space(3))) uint32_t*)l,
        4, 0, 0);
}

__global__ __launch_bounds__(256) void dwconv_gate_dma(
    const float* __restrict__ x,
    const float* __restrict__ kern,
    const float* __restrict__ alpha,
    const float* __restrict__ bias,
    float* __restrict__ out)
{
    __shared__ float smem[NWAVES * WAVE_F];   // 30720 B

    const int tid  = threadIdx.x;
    const int lane = tid & 63;
    const int wave = tid >> 6;
    float* swave = &smem[wave * WAVE_F];      // wave-uniform

    // XCD-aware swizzle: hw-bid k mod 8 -> XCD k; give XCD k the logical
    // range [k*504, (k+1)*504) so blocks sharing rows co-reside on one L2.
    const int bid = (blockIdx.x & 7) * BPX + (blockIdx.x >> 3);

    const int gid = bid * 256 + tid;
    // gid -> (b, chunk, w, c); c innermost for coalescing
    const int c     = gid % CH;
    const int r1    = gid / CH;
    const int w     = r1 % WI;
    const int r2    = r1 / WI;
    const int chunk = r2 % NSPLIT;
    const int b     = r2 / NSPLIT;

    const float alphav = alpha[0];
    const float biasv  = bias[0];

    // Clamped tap offsets; OOB dx columns killed by zeroed weights.
    int toff[5];
#pragma unroll
    for (int dx = 0; dx < 5; ++dx) {
        const int ww = w + dx - 2;
        const int wc = ww < 0 ? 0 : (ww >= WI ? WI - 1 : ww);
        toff[dx] = (wc - w) * CH;
    }
    float wt[25];
#pragma unroll
    for (int i = 0; i < 25; ++i) {
        const int dx = i % 5;
        const int ww = w + dx - 2;
        wt[i] = ((ww >= 0) && (ww < WI)) ? kern[i * CH + c] : 0.f;
    }

    const int h0   = chunk * CHUNK_ROWS;
    const int rows = (chunk == NSPLIT - 1) ? (HI - h0) : CHUNK_ROWS;
    const int nit  = rows + 4;               // 42 / 42 / 40

    const float* px = x   + (size_t)b * IMG_STRIDE + (size_t)w * CH + c;
    float*       po = out + (size_t)b * IMG_STRIDE + (size_t)w * CH + c;

    // Issue all 5 tap DMAs for input row RIN (clamped) into SLOT.
#define ISSUE(SLOT, RIN) do {                                              \
        const int _q  = (RIN);                                             \
        const int _qc = _q < 0 ? 0 : (_q >= HI ? HI - 1 : _q);             \
        const float* _g = px + (size_t)_qc * ROW_STRIDE;                   \
        float* _d = swave + (SLOT) * SLOT_F;                               \
        dma4(_g + toff[0], _d);                                            \
        dma4(_g + toff[1], _d + 64);                                       \
        dma4(_g + toff[2], _d + 128);                                      \
        dma4(_g + toff[3], _d + 192);                                      \
        dma4(_g + toff[4], _d + 256);                                      \
    } while (0)

    // Prologue: 6 rows (30 loads) in flight.
    ISSUE(0, h0 - 2);
    ISSUE(1, h0 - 1);
    ISSUE(2, h0);
    ISSUE(3, h0 + 1);
    ISSUE(4, h0 + 2);
    ISSUE(5, h0 + 3);

    float acc[5] = {0.f, 0.f, 0.f, 0.f, 0.f};
    float xp1 = 0.f, xp2 = 0.f;   // center-tap history (delay 2)

    // Body _i (slot = _i % 6): wait row _i's loads (drain to 25 = newest
    // 5 rows' loads, assuming stores retired -- conservative), consume,
    // reissue slot for row _i + 6.
#define BODY(I, SLOT) do {                                                 \
        const int _i = (I);                                                \
        asm volatile("s_waitcnt vmcnt(25)" ::: "memory");                  \
        const int _rin = h0 - 2 + _i;                                      \
        const bool _rok = (_rin >= 0) && (_rin < HI);  /* wave-uniform */  \
        float t0, t1, t2, t3, t4;                                          \
        if (_rok) {                                                        \
            const float* _s = swave + (SLOT) * SLOT_F + lane;              \
            t0 = _s[0];   t1 = _s[64];  t2 = _s[128];                      \
            t3 = _s[192]; t4 = _s[256];                                    \
        } else {                                                           \
            t0 = 0.f; t1 = 0.f; t2 = 0.f; t3 = 0.f; t4 = 0.f;              \
        }                                                                  \
        _Pragma("unroll")                                                  \
        for (int j = 0; j < 5; ++j) {                                      \
            const int wb = (4 - j) * 5;                                    \
            acc[j] = fmaf(t0, wt[wb + 0], acc[j]);                         \
            acc[j] = fmaf(t1, wt[wb + 1], acc[j]);                         \
            acc[j] = fmaf(t2, wt[wb + 2], acc[j]);                         \
            acc[j] = fmaf(t3, wt[wb + 3], acc[j]);                         \
            acc[j] = fmaf(t4, wt[wb + 4], acc[j]);                         \
        }                                                                  \
        if (_i >= 4) {                                                     \
            const float g = fmaf(acc[0], alphav, biasv);                   \
            __builtin_nontemporal_store(                                   \
                fmaf(g, xp2, xp2),                                         \
                po + (ptrdiff_t)(h0 - 4 + _i) * ROW_STRIDE);               \
        }                                                                  \
        xp2 = xp1; xp1 = t2;                                               \
        acc[0] = acc[1]; acc[1] = acc[2]; acc[2] = acc[3];                 \
        acc[3] = acc[4]; acc[4] = 0.f;                                     \
        ISSUE(SLOT, h0 + 4 + _i);                                          \
    } while (0)

    int i = 0;
    for (; i + 6 <= nit; i += 6) {
        BODY(i + 0, 0);
        BODY(i + 1, 1);
        BODY(i + 2, 2);
        BODY(i + 3, 3);
        BODY(i + 4, 4);
        BODY(i + 5, 5);
    }
    // nit % 6 is 0 (42) or 4 (40), never anything else.
    if (i < nit) {
        BODY(i + 0, 0);
        BODY(i + 1, 1);
        BODY(i + 2, 2);
        BODY(i + 3, 3);
    }
#undef BODY
#undef ISSUE
}

extern "C" void kernel_launch(void* const* d_in, const int* in_sizes, int n_in,
                              void* d_out, int out_size, void* d_ws, size_t ws_size,
                              hipStream_t stream) {
    const float* x     = (const float*)d_in[0];
    const float* kern  = (const float*)d_in[1];
    const float* alpha = (const float*)d_in[2];
    const float* bias  = (const float*)d_in[3];
    float* out = (float*)d_out;

    dim3 block(256);
    dim3 grid(NBLK);                              // 4032 blocks, 16128 waves
    hipLaunchKernelGGL(dwconv_gate_dma, grid, block, 0, stream,
                       x, kern, alpha, bias, out);
}

// Round 17
// 62.256 us; speedup vs baseline: 1.4121x; 1.1868x over previous
//
#include <hip/hip_runtime.h>
#include <stdint.h>

// Depthwise 5x5 SAME conv + gate residual: out = x*(alpha*conv + bias) + x
// x: (B=32, H=112, W=112, C=96) f32 NHWC. kernel: (5,5,96) f32.
//
// R17 = R16 with the compile fix: __builtin_nontemporal_store requires a
// NATIVE vector type, not HIP's float4 struct -> use ext_vector_type(4).
// Design unchanged (float4-wide DMA LDS ring):
//  - 5 x global_load_lds width=16 per row (vs 20 width=4), 5 x
//    ds_read_b128 (vs 20 ds_read_b32), 1 NT 16B store (vs 4x4B).
//  - 192-thread blocks (24 c4 x 8 w); 1344 blocks = 8 x 168 -> clean
//    XCD swizzle (R13's win: FETCH 209->77 MB).
//  - SLOTS=3 (R14: deeper is null), 45 KB LDS/block -> 3 blocks/CU ->
//    9 waves/CU, ~10 KB in flight per wave.
//  - Exact peeled vmcnt counting interleaved NT stores:
//    bodies 0-4: 10, body 5: 11, steady: 12.
//  - Kept: clamped toff + zeroed weight dx-columns (W edges), block-
//    uniform H-edge zeroing at consume, always-issue clamped DMA rows.

typedef float f4 __attribute__((ext_vector_type(4)));

#define CHN   96
#define C4    24                 // float4 channel groups
#define WI    112
#define HI    112
#define BATCH 32
#define NSPLIT 3
#define CHUNK_ROWS 38            // chunks: 38, 38, 36 -> nit 42/42/40
#define ROW   (WI * CHN)         // 10752 floats
#define IMG   ((size_t)HI * ROW)
#define NTHR  192                // 3 waves = 24 c4 x 8 w
#define NBLK  (BATCH * NSPLIT * WI * C4 / NTHR)  // 1344
#define BPX   (NBLK / 8)         // 168 blocks per XCD

#define SLOTS  3
#define SLOT4  (5 * 64)          // 5 taps x 64 lanes (f4 units)
#define WAVE4  (SLOTS * SLOT4)   // 960 f4 per wave
#define NWAVES 3

__device__ __forceinline__ void dma16(const float* g, f4* l) {
    __builtin_amdgcn_global_load_lds(
        (const __attribute__((address_space(1))) uint32_t*)g,
        (__attribute__((address_space(3))) uint32_t*)l,
        16, 0, 0);
}

__device__ __forceinline__ void fma4(f4& a, const f4 t, const f4 v) {
    a.x = fmaf(t.x, v.x, a.x);
    a.y = fmaf(t.y, v.y, a.y);
    a.z = fmaf(t.z, v.z, a.z);
    a.w = fmaf(t.w, v.w, a.w);
}

__global__ __launch_bounds__(NTHR, 2) void dwconv_gate_dma4(
    const float* __restrict__ x,
    const float* __restrict__ kern,
    const float* __restrict__ alpha,
    const float* __restrict__ bias,
    float* __restrict__ out)
{
    __shared__ f4 smem[NWAVES * WAVE4];   // 46080 B

    const int tid  = threadIdx.x;
    const int lane = tid & 63;
    const int wave = tid >> 6;
    f4* swave = &smem[wave * WAVE4];      // wave-uniform

    // XCD-aware swizzle: hw-bid k mod 8 -> XCD k; XCD k gets logical range
    // [k*168, (k+1)*168) so blocks sharing rows co-reside on one L2.
    const int bid = (blockIdx.x & 7) * BPX + (blockIdx.x >> 3);

    const int gid = bid * NTHR + tid;
    // gid -> (b, chunk, w, c4); c4 innermost for coalescing.
    const int c4    = gid % C4;
    const int rest  = gid / C4;
    const int w     = rest % WI;
    const int r2    = rest / WI;             // block-uniform (8 | 112)
    const int chunk = r2 % NSPLIT;
    const int b     = r2 / NSPLIT;

    const float av = alpha[0];
    const float bv = bias[0];
    const f4 z4 = {0.f, 0.f, 0.f, 0.f};

    // Clamped tap offsets (floats); OOB dx columns killed by zeroed weights.
    int toff[5];
#pragma unroll
    for (int dx = 0; dx < 5; ++dx) {
        const int ww = w + dx - 2;
        const int wc = ww < 0 ? 0 : (ww >= WI ? WI - 1 : ww);
        toff[dx] = (wc - w) * CHN;
    }
    f4 wt[25];
#pragma unroll
    for (int i = 0; i < 25; ++i) {
        const int ww = w + (i % 5) - 2;
        wt[i] = ((ww >= 0) && (ww < WI))
              ? *(const f4*)(kern + i * CHN + 4 * c4) : z4;
    }

    const int h0   = chunk * CHUNK_ROWS;
    const int rows = (chunk == NSPLIT - 1) ? (HI - h0) : CHUNK_ROWS;
    const int nit  = rows + 4;               // 42 / 42 / 40

    const float* px = x   + (size_t)b * IMG + (size_t)w * CHN + 4 * c4;
    float*       po = out + (size_t)b * IMG + (size_t)w * CHN + 4 * c4;

    // Issue 5 width-16 DMAs for input row RIN (clamped) into SLOT.
#define ISSUE(SLOT, RIN) do {                                              \
        const int _q  = (RIN);                                             \
        const int _qc = _q < 0 ? 0 : (_q >= HI ? HI - 1 : _q);             \
        const float* _g = px + (size_t)_qc * ROW;                          \
        dma16(_g + toff[0], swave + (SLOT) * SLOT4);                       \
        dma16(_g + toff[1], swave + (SLOT) * SLOT4 + 64);                  \
        dma16(_g + toff[2], swave + (SLOT) * SLOT4 + 128);                 \
        dma16(_g + toff[3], swave + (SLOT) * SLOT4 + 192);                 \
        dma16(_g + toff[4], swave + (SLOT) * SLOT4 + 256);                 \
    } while (0)

    // Prologue: 3 rows (15 loads) in flight.
    ISSUE(0, h0 - 2);
    ISSUE(1, h0 - 1);
    ISSUE(2, h0);

    f4 acc[5] = {z4, z4, z4, z4, z4};
    f4 xp1 = z4, xp2 = z4;   // center-tap history (delay 2)

    // Body _i (slot = _i % 3): wait row _i's 5 loads (exact count incl.
    // interleaved NT stores), ds_read 5 taps, 100 FMAs, NT store, reissue
    // slot for row _i + 3.
#define BODY(I, SLOT, VMC) do {                                            \
        const int _i = (I);                                                \
        asm volatile("s_waitcnt vmcnt(" #VMC ")" ::: "memory");            \
        const int _rin = h0 - 2 + _i;                                      \
        const bool _rok = (_rin >= 0) && (_rin < HI);  /* block-uniform */ \
        f4 t0, t1, t2, t3, t4;                                             \
        if (_rok) {                                                        \
            const f4* _s = swave + (SLOT) * SLOT4 + lane;                  \
            t0 = _s[0];   t1 = _s[64];  t2 = _s[128];                      \
            t3 = _s[192]; t4 = _s[256];                                    \
        } else {                                                           \
            t0 = z4; t1 = z4; t2 = z4; t3 = z4; t4 = z4;                   \
        }                                                                  \
        _Pragma("unroll")                                                  \
        for (int j = 0; j < 5; ++j) {                                      \
            const int wb = (4 - j) * 5;                                    \
            fma4(acc[j], t0, wt[wb + 0]);                                  \
            fma4(acc[j], t1, wt[wb + 1]);                                  \
            fma4(acc[j], t2, wt[wb + 2]);                                  \
            fma4(acc[j], t3, wt[wb + 3]);                                  \
            fma4(acc[j], t4, wt[wb + 4]);                                  \
        }                                                                  \
        if (_i >= 4) {                                                     \
            f4 o;                                                          \
            o.x = fmaf(fmaf(acc[0].x, av, bv), xp2.x, xp2.x);              \
            o.y = fmaf(fmaf(acc[0].y, av, bv), xp2.y, xp2.y);              \
            o.z = fmaf(fmaf(acc[0].z, av, bv), xp2.z, xp2.z);              \
            o.w = fmaf(fmaf(acc[0].w, av, bv), xp2.w, xp2.w);              \
            __builtin_nontemporal_store(                                   \
                o, (f4*)(po + (ptrdiff_t)(h0 - 4 + _i) * ROW));            \
        }                                                                  \
        xp2 = xp1; xp1 = t2;                                               \
        acc[0] = acc[1]; acc[1] = acc[2]; acc[2] = acc[3];                 \
        acc[3] = acc[4]; acc[4] = z4;                                      \
        ISSUE(SLOT, h0 + 1 + _i);                                          \
    } while (0)

    // Peeled prologue bodies with exact vmcnt:
    //  bodies 0-4: 15 loads outstanding, no stores yet -> 10
    //  body 5: [r5,r6,store4,r7] = 16 -> 11
    //  body >=6 steady: [r_i, store, r_i+1, store, r_i+2] = 17-18 -> 12
    BODY(0, 0, 10);
    BODY(1, 1, 10);
    BODY(2, 2, 10);
    BODY(3, 0, 10);
    BODY(4, 1, 10);
    BODY(5, 2, 11);

    int i = 6;
    for (; i + 3 <= nit; i += 3) {     // slot pattern stays 0,1,2
        BODY(i + 0, 0, 12);
        BODY(i + 1, 1, 12);
        BODY(i + 2, 2, 12);
    }
    if (i < nit) BODY(i, 0, 12);       // nit % 3 is 0 or 1, never 2
#undef BODY
#undef ISSUE
}

extern "C" void kernel_launch(void* const* d_in, const int* in_sizes, int n_in,
                              void* d_out, int out_size, void* d_ws, size_t ws_size,
                              hipStream_t stream) {
    const float* x     = (const float*)d_in[0];
    const float* kern  = (const float*)d_in[1];
    const float* alpha = (const float*)d_in[2];
    const float* bias  = (const float*)d_in[3];
    float* out = (float*)d_out;

    dim3 block(NTHR);
    dim3 grid(NBLK);                   // 1344 blocks, 4032 waves
    hipLaunchKernelGGL(dwconv_gate_dma4, grid, block, 0, stream,
                       x, kern, alpha, bias, out);
}

// Round 18
// 54.307 us; speedup vs baseline: 1.6188x; 1.1464x over previous
//
#include <hip/hip_runtime.h>
#include <stdint.h>

// Depthwise 5x5 SAME conv + gate residual: out = x*(alpha*conv + bias) + x
// x: (B=32, H=112, W=112, C=96) f32 NHWC. kernel: (5,5,96) f32.
//
// R18 = R17 (float4 DMA ring, 62.3us) restructured for occupancy:
//  - Cooperative wave staging: wave = 8 w x 8 c4 lanes; per row the wave
//    stages its OWN (12 w-halo x 8 c4) tile with TWO width-16 DMAs
//    (issue1: tile[lane], issue2: tile[64+min(lane,31)], clamped dup for
//    lanes 32-63 -> no exec-mask games). Taps come from the wave tile:
//    ds_read_b128 at (w_sub+dx)*8 + c4sub -- conflict-free.
//    LDS 46->24.6 KB/block; DMA issues 5->2 per row per wave.
//  - NSPLIT 3->6 (chunks 19x5+17; nit 23/21): 2688 blocks = 8 x 336,
//    XCD-swizzle-clean, demand 10.5 blocks/CU -> saturates the VGPR cap
//    (~16 waves/CU, ~1.8x current residency).
//  - W-edge: staged addresses clamped to the row; consuming lanes whose
//    (w+dx-2) is OOB have that wt column zeroed (proven R5-R17).
//  - H-edge: block-uniform rok zeroing at consume; DMAs always clamped.
//  - Exact peeled vmcnt (2 loads/row): 6,6,6,6,6,7,8 then steady 9.
//  - Kept: NT f4 stores, no barriers (wave-private slots).

typedef float f4 __attribute__((ext_vector_type(4)));

#define CHN   96
#define WI    112
#define HI    112
#define BATCH 32
#define NSPLIT 6
#define CHUNK_ROWS 19            // chunks: 19,19,19,19,19,17 -> nit 23/21
#define ROW   (WI * CHN)         // 10752 floats
#define IMG   ((size_t)HI * ROW)
#define NTHR  192                // 3 waves; wave k owns c4 in [8k, 8k+8)
#define NWG   14                 // w-groups of 8
#define NBLK  (BATCH * NSPLIT * NWG)   // 2688
#define BPX   (NBLK / 8)         // 336 blocks per XCD

#define SLOTS  4
#define SLOT4  128               // 12w x 8c4 = 96 f4 used, padded to 128
#define WAVE4  (SLOTS * SLOT4)   // 512 f4 per wave
#define NWAVES 3                 // LDS total: 3*512*16 = 24576 B

__device__ __forceinline__ void dma16(const float* g, f4* l) {
    __builtin_amdgcn_global_load_lds(
        (const __attribute__((address_space(1))) uint32_t*)g,
        (__attribute__((address_space(3))) uint32_t*)l,
        16, 0, 0);
}

__device__ __forceinline__ void fma4(f4& a, const f4 t, const f4 v) {
    a.x = fmaf(t.x, v.x, a.x);
    a.y = fmaf(t.y, v.y, a.y);
    a.z = fmaf(t.z, v.z, a.z);
    a.w = fmaf(t.w, v.w, a.w);
}

__global__ __launch_bounds__(NTHR, 2) void dwconv_gate_coop(
    const float* __restrict__ x,
    const float* __restrict__ kern,
    const float* __restrict__ alpha,
    const float* __restrict__ bias,
    float* __restrict__ out)
{
    __shared__ f4 smem[NWAVES * WAVE4];

    const int tid   = threadIdx.x;
    const int lane  = tid & 63;
    const int wave  = tid >> 6;            // c4 group: c4 = wave*8 + c4sub
    const int c4sub = lane & 7;
    const int wsub  = lane >> 3;           // 0..7
    f4* swave = &smem[wave * WAVE4];       // wave-uniform

    // XCD-aware swizzle (2688 = 8 x 336).
    const int bid = (blockIdx.x & 7) * BPX + (blockIdx.x >> 3);

    // bid -> (b, chunk, wg); all block-uniform.
    const int wg    = bid % NWG;
    const int chunk = (bid / NWG) % NSPLIT;
    const int b     = bid / (NWG * NSPLIT);

    const int w0 = wg * 8;
    const int w  = w0 + wsub;              // this lane's output column
    const int c4 = wave * 8 + c4sub;

    const float av = alpha[0];
    const float bv = bias[0];
    const f4 z4 = {0.f, 0.f, 0.f, 0.f};

    // Weights; zero dx columns whose (w + dx - 2) is outside [0, WI).
    f4 wt[25];
#pragma unroll
    for (int i = 0; i < 25; ++i) {
        const int ww = w + (i % 5) - 2;
        wt[i] = ((ww >= 0) && (ww < WI))
              ? *(const f4*)(kern + i * CHN + 4 * c4) : z4;
    }

    const int h0   = chunk * CHUNK_ROWS;
    const int rows = (chunk == NSPLIT - 1) ? (HI - h0) : CHUNK_ROWS;
    const int nit  = rows + 4;             // 23 or 21

    const float* gx = x   + (size_t)b * IMG;
    float*       po = out + (size_t)b * IMG + (size_t)w * CHN + 4 * c4;

    // Per-lane staging source column offsets (floats), clamped to the row.
    // Tile entry t -> w_l = t/8 (0..11), c4_l = t%8; col = w0 - 2 + w_l.
    const int t1 = lane;
    const int t2 = 64 + (lane < 32 ? lane : 31);   // dup for lanes 32-63
    const int w1 = w0 - 2 + (t1 >> 3);
    const int w2 = w0 - 2 + (t2 >> 3);
    const int w1c = w1 < 0 ? 0 : (w1 >= WI ? WI - 1 : w1);
    const int w2c = w2 < 0 ? 0 : (w2 >= WI ? WI - 1 : w2);
    const int coff1 = w1c * CHN + 4 * (wave * 8 + (t1 & 7));
    const int coff2 = w2c * CHN + 4 * (wave * 8 + (t2 & 7));

    // Issue the 2 staging DMAs for input row RIN (clamped) into SLOT.
#define ISSUE(SLOT, RIN) do {                                              \
        const int _q  = (RIN);                                             \
        const int _qc = _q < 0 ? 0 : (_q >= HI ? HI - 1 : _q);             \
        const float* _r = gx + (size_t)_qc * ROW;                          \
        dma16(_r + coff1, swave + (SLOT) * SLOT4);                         \
        dma16(_r + coff2, swave + (SLOT) * SLOT4 + 64);                    \
    } while (0)

    // Prologue: 4 rows (8 loads) in flight.
    ISSUE(0, h0 - 2);
    ISSUE(1, h0 - 1);
    ISSUE(2, h0);
    ISSUE(3, h0 + 1);

    f4 acc[5] = {z4, z4, z4, z4, z4};
    f4 xp1 = z4, xp2 = z4;   // center-tap history (delay 2)

    const int rbase = wsub * 8 + c4sub;    // tile index of dx=0 tap

    // Body _i (slot = _i & 3): wait row _i's 2 loads, read 5 taps from the
    // wave tile, 100 FMAs, NT store, reissue slot for row _i + 4.
#define BODY(I, SLOT, VMC) do {                                            \
        const int _i = (I);                                                \
        asm volatile("s_waitcnt vmcnt(" #VMC ")" ::: "memory");            \
        const int _rin = h0 - 2 + _i;                                      \
        const bool _rok = (_rin >= 0) && (_rin < HI);  /* block-uniform */ \
        f4 t0, t1v, t2v, t3, t4;                                           \
        if (_rok) {                                                        \
            const f4* _s = swave + (SLOT) * SLOT4 + rbase;                 \
            t0  = _s[0];  t1v = _s[8];  t2v = _s[16];                      \
            t3  = _s[24]; t4  = _s[32];                                    \
        } else {                                                           \
            t0 = z4; t1v = z4; t2v = z4; t3 = z4; t4 = z4;                 \
        }                                                                  \
        _Pragma("unroll")                                                  \
        for (int j = 0; j < 5; ++j) {                                      \
            const int wb = (4 - j) * 5;                                    \
            fma4(acc[j], t0,  wt[wb + 0]);                                 \
            fma4(acc[j], t1v, wt[wb + 1]);                                 \
            fma4(acc[j], t2v, wt[wb + 2]);                                 \
            fma4(acc[j], t3,  wt[wb + 3]);                                 \
            fma4(acc[j], t4,  wt[wb + 4]);                                 \
        }                                                                  \
        if (_i >= 4) {                                                     \
            f4 o;                                                          \
            o.x = fmaf(fmaf(acc[0].x, av, bv), xp2.x, xp2.x);              \
            o.y = fmaf(fmaf(acc[0].y, av, bv), xp2.y, xp2.y);              \
            o.z = fmaf(fmaf(acc[0].z, av, bv), xp2.z, xp2.z);              \
            o.w = fmaf(fmaf(acc[0].w, av, bv), xp2.w, xp2.w);              \
            __builtin_nontemporal_store(                                   \
                o, (f4*)(po + (ptrdiff_t)(h0 - 4 + _i) * ROW));            \
        }                                                                  \
        xp2 = xp1; xp1 = t2v;                                              \
        acc[0] = acc[1]; acc[1] = acc[2]; acc[2] = acc[3];                 \
        acc[3] = acc[4]; acc[4] = z4;                                      \
        ISSUE(SLOT, h0 + 2 + _i);                                          \
    } while (0)

    // Peeled prologue (exact vmcnt; 2 loads/row, stores join from body 4):
    BODY(0, 0, 6);
    BODY(1, 1, 6);
    BODY(2, 2, 6);
    BODY(3, 3, 6);
    BODY(4, 0, 6);
    BODY(5, 1, 7);
    BODY(6, 2, 8);

    int i = 7;
    for (; i + 4 <= nit; i += 4) {         // nit=23: 7..22 (16 = 4x4)
        BODY(i + 0, 3, 9);
        BODY(i + 1, 0, 9);
        BODY(i + 2, 1, 9);
        BODY(i + 3, 2, 9);
    }
    for (; i < nit; ++i) {                 // nit=21: 2 leftover bodies
        BODY(i, (i & 3) == 0 ? 0 : ((i & 3) == 1 ? 1 : ((i & 3) == 2 ? 2 : 3)), 9);
    }
#undef BODY
#undef ISSUE
}

extern "C" void kernel_launch(void* const* d_in, const int* in_sizes, int n_in,
                              void* d_out, int out_size, void* d_ws, size_t ws_size,
                              hipStream_t stream) {
    const float* x     = (const float*)d_in[0];
    const float* kern  = (const float*)d_in[1];
    const float* alpha = (const float*)d_in[2];
    const float* bias  = (const float*)d_in[3];
    float* out = (float*)d_out;

    dim3 block(NTHR);
    dim3 grid(NBLK);                       // 2688 blocks, 8064 waves
    hipLaunchKernelGGL(dwconv_gate_coop, grid, block, 0, stream,
                       x, kern, alpha, bias, out);
}

// Round 19
// 51.826 us; speedup vs baseline: 1.6963x; 1.0479x over previous
//
#include <hip/hip_runtime.h>
#include <stdint.h>

// Depthwise 5x5 SAME conv + gate residual: out = x*(alpha*conv + bias) + x
// x: (B=32, H=112, W=112, C=96) f32 NHWC. kernel: (5,5,96) f32.
//
// R19 = R18 (54.3us: coop wave staging + NSPLIT=6 + XCD swizzle + NT)
// + ONE change: compile-time trimmed FMA ranges in prologue/epilogue.
// Body i only accumulates j in [max(0,4-i), min(5, nit-i)): the trimmed
// j's feed outputs outside this chunk (discarded by the ring shift before
// any store) -- 20 of 115 FMA-groups per chunk (~17% of FMA work) were
// dead. ISSUE/vmcnt schedule is byte-identical to R18 (memory op counts
// unchanged); the two tail shapes (rows 19 vs 17) take a block-uniform
// branch with fully peeled trimmed bodies.

typedef float f4 __attribute__((ext_vector_type(4)));

#define CHN   96
#define WI    112
#define HI    112
#define BATCH 32
#define NSPLIT 6
#define CHUNK_ROWS 19            // chunks: 19,19,19,19,19,17 -> nit 23/21
#define ROW   (WI * CHN)         // 10752 floats
#define IMG   ((size_t)HI * ROW)
#define NTHR  192                // 3 waves; wave k owns c4 in [8k, 8k+8)
#define NWG   14                 // w-groups of 8
#define NBLK  (BATCH * NSPLIT * NWG)   // 2688
#define BPX   (NBLK / 8)         // 336 blocks per XCD

#define SLOTS  4
#define SLOT4  128               // 12w x 8c4 = 96 f4 used, padded to 128
#define WAVE4  (SLOTS * SLOT4)   // 512 f4 per wave
#define NWAVES 3                 // LDS total: 3*512*16 = 24576 B

__device__ __forceinline__ void dma16(const float* g, f4* l) {
    __builtin_amdgcn_global_load_lds(
        (const __attribute__((address_space(1))) uint32_t*)g,
        (__attribute__((address_space(3))) uint32_t*)l,
        16, 0, 0);
}

__device__ __forceinline__ void fma4(f4& a, const f4 t, const f4 v) {
    a.x = fmaf(t.x, v.x, a.x);
    a.y = fmaf(t.y, v.y, a.y);
    a.z = fmaf(t.z, v.z, a.z);
    a.w = fmaf(t.w, v.w, a.w);
}

__global__ __launch_bounds__(NTHR, 2) void dwconv_gate_coop(
    const float* __restrict__ x,
    const float* __restrict__ kern,
    const float* __restrict__ alpha,
    const float* __restrict__ bias,
    float* __restrict__ out)
{
    __shared__ f4 smem[NWAVES * WAVE4];

    const int tid   = threadIdx.x;
    const int lane  = tid & 63;
    const int wave  = tid >> 6;            // c4 group: c4 = wave*8 + c4sub
    const int c4sub = lane & 7;
    const int wsub  = lane >> 3;           // 0..7
    f4* swave = &smem[wave * WAVE4];       // wave-uniform

    // XCD-aware swizzle (2688 = 8 x 336).
    const int bid = (blockIdx.x & 7) * BPX + (blockIdx.x >> 3);

    // bid -> (b, chunk, wg); all block-uniform.
    const int wg    = bid % NWG;
    const int chunk = (bid / NWG) % NSPLIT;
    const int b     = bid / (NWG * NSPLIT);

    const int w0 = wg * 8;
    const int w  = w0 + wsub;              // this lane's output column
    const int c4 = wave * 8 + c4sub;

    const float av = alpha[0];
    const float bv = bias[0];
    const f4 z4 = {0.f, 0.f, 0.f, 0.f};

    // Weights; zero dx columns whose (w + dx - 2) is outside [0, WI).
    f4 wt[25];
#pragma unroll
    for (int i = 0; i < 25; ++i) {
        const int ww = w + (i % 5) - 2;
        wt[i] = ((ww >= 0) && (ww < WI))
              ? *(const f4*)(kern + i * CHN + 4 * c4) : z4;
    }

    const int h0   = chunk * CHUNK_ROWS;
    const int rows = (chunk == NSPLIT - 1) ? (HI - h0) : CHUNK_ROWS;

    const float* gx = x   + (size_t)b * IMG;
    float*       po = out + (size_t)b * IMG + (size_t)w * CHN + 4 * c4;

    // Per-lane staging source column offsets (floats), clamped to the row.
    // Tile entry t -> w_l = t/8 (0..11), c4_l = t%8; col = w0 - 2 + w_l.
    const int t1 = lane;
    const int t2 = 64 + (lane < 32 ? lane : 31);   // dup for lanes 32-63
    const int w1 = w0 - 2 + (t1 >> 3);
    const int w2 = w0 - 2 + (t2 >> 3);
    const int w1c = w1 < 0 ? 0 : (w1 >= WI ? WI - 1 : w1);
    const int w2c = w2 < 0 ? 0 : (w2 >= WI ? WI - 1 : w2);
    const int coff1 = w1c * CHN + 4 * (wave * 8 + (t1 & 7));
    const int coff2 = w2c * CHN + 4 * (wave * 8 + (t2 & 7));

    // Issue the 2 staging DMAs for input row RIN (clamped) into SLOT.
#define ISSUE(SLOT, RIN) do {                                              \
        const int _q  = (RIN);                                             \
        const int _qc = _q < 0 ? 0 : (_q >= HI ? HI - 1 : _q);             \
        const float* _r = gx + (size_t)_qc * ROW;                          \
        dma16(_r + coff1, swave + (SLOT) * SLOT4);                         \
        dma16(_r + coff2, swave + (SLOT) * SLOT4 + 64);                    \
    } while (0)

    // Prologue: 4 rows (8 loads) in flight.
    ISSUE(0, h0 - 2);
    ISSUE(1, h0 - 1);
    ISSUE(2, h0);
    ISSUE(3, h0 + 1);

    f4 acc[5] = {z4, z4, z4, z4, z4};
    f4 xp1 = z4, xp2 = z4;   // center-tap history (delay 2)

    const int rbase = wsub * 8 + c4sub;    // tile index of dx=0 tap

    // Body _i (slot = _i & 3): wait row _i's 2 loads, read 5 taps from the
    // wave tile, FMAs for j in [JLO, JHI) only (trimmed outputs fall
    // outside this chunk), NT store, reissue slot for row _i + 4.
#define BODY(I, SLOT, VMC, JLO, JHI) do {                                  \
        const int _i = (I);                                                \
        asm volatile("s_waitcnt vmcnt(" #VMC ")" ::: "memory");            \
        const int _rin = h0 - 2 + _i;                                      \
        const bool _rok = (_rin >= 0) && (_rin < HI);  /* block-uniform */ \
        f4 t0, t1v, t2v, t3, t4;                                           \
        if (_rok) {                                                        \
            const f4* _s = swave + (SLOT) * SLOT4 + rbase;                 \
            t0  = _s[0];  t1v = _s[8];  t2v = _s[16];                      \
            t3  = _s[24]; t4  = _s[32];                                    \
        } else {                                                           \
            t0 = z4; t1v = z4; t2v = z4; t3 = z4; t4 = z4;                 \
        }                                                                  \
        _Pragma("unroll")                                                  \
        for (int j = (JLO); j < (JHI); ++j) {                              \
            const int wb = (4 - j) * 5;                                    \
            fma4(acc[j], t0,  wt[wb + 0]);                                 \
            fma4(acc[j], t1v, wt[wb + 1]);                                 \
            fma4(acc[j], t2v, wt[wb + 2]);                                 \
            fma4(acc[j], t3,  wt[wb + 3]);                                 \
            fma4(acc[j], t4,  wt[wb + 4]);                                 \
        }                                                                  \
        if (_i >= 4) {                                                     \
            f4 o;                                                          \
            o.x = fmaf(fmaf(acc[0].x, av, bv), xp2.x, xp2.x);              \
            o.y = fmaf(fmaf(acc[0].y, av, bv), xp2.y, xp2.y);              \
            o.z = fmaf(fmaf(acc[0].z, av, bv), xp2.z, xp2.z);              \
            o.w = fmaf(fmaf(acc[0].w, av, bv), xp2.w, xp2.w);              \
            __builtin_nontemporal_store(                                   \
                o, (f4*)(po + (ptrdiff_t)(h0 - 4 + _i) * ROW));            \
        }                                                                  \
        xp2 = xp1; xp1 = t2v;                                              \
        acc[0] = acc[1]; acc[1] = acc[2]; acc[2] = acc[3];                 \
        acc[3] = acc[4]; acc[4] = z4;                                      \
        ISSUE(SLOT, h0 + 2 + _i);                                          \
    } while (0)

    // Prologue bodies: trimmed JLO = 4-i (outputs below h0 are discarded
    // by the ring shift before any store). Exact vmcnt as R18.
    BODY(0, 0, 6, 4, 5);
    BODY(1, 1, 6, 3, 5);
    BODY(2, 2, 6, 2, 5);
    BODY(3, 3, 6, 1, 5);
    BODY(4, 0, 6, 0, 5);
    BODY(5, 1, 7, 0, 5);
    BODY(6, 2, 8, 0, 5);

    if (rows == CHUNK_ROWS) {              // nit = 23
        for (int i = 7; i + 4 <= 19; i += 4) {   // bodies 7..18 (3 x 4)
            BODY(i + 0, 3, 9, 0, 5);
            BODY(i + 1, 0, 9, 0, 5);
            BODY(i + 2, 1, 9, 0, 5);
            BODY(i + 3, 2, 9, 0, 5);
        }
        // Epilogue: JHI = nit - i (higher j feed rows >= h0+rows).
        BODY(19, 3, 9, 0, 4);
        BODY(20, 0, 9, 0, 3);
        BODY(21, 1, 9, 0, 2);
        BODY(22, 2, 9, 0, 1);
    } else {                               // rows = 17, nit = 21
        for (int i = 7; i + 4 <= 15; i += 4) {   // bodies 7..14 (2 x 4)
            BODY(i + 0, 3, 9, 0, 5);
            BODY(i + 1, 0, 9, 0, 5);
            BODY(i + 2, 1, 9, 0, 5);
            BODY(i + 3, 2, 9, 0, 5);
        }
        BODY(15, 3, 9, 0, 5);
        BODY(16, 0, 9, 0, 5);
        // Epilogue trimmed.
        BODY(17, 1, 9, 0, 4);
        BODY(18, 2, 9, 0, 3);
        BODY(19, 3, 9, 0, 2);
        BODY(20, 0, 9, 0, 1);
    }
#undef BODY
#undef ISSUE
}

extern "C" void kernel_launch(void* const* d_in, const int* in_sizes, int n_in,
                              void* d_out, int out_size, void* d_ws, size_t ws_size,
                              hipStream_t stream) {
    const float* x     = (const float*)d_in[0];
    const float* kern  = (const float*)d_in[1];
    const float* alpha = (const float*)d_in[2];
    const float* bias  = (const float*)d_in[3];
    float* out = (float*)d_out;

    dim3 block(NTHR);
    dim3 grid(NBLK);                       // 2688 blocks, 8064 waves
    hipLaunchKernelGGL(dwconv_gate_coop, grid, block, 0, stream,
                       x, kern, alpha, bias, out);
}